// Round 4
// baseline (108.976 us; speedup 1.0000x reference)
//
#include <hip/hip_runtime.h>

// Problem constants (from reference setup_inputs): B=8, N=16384, K=64
#define BB 8
#define NN 16384
#define KK 64
#define GRID_FUSED 2048

#if __has_builtin(__builtin_amdgcn_exp2f)
#define EXP2(x) __builtin_amdgcn_exp2f(x)
#else
#define EXP2(x) exp2f(x)
#endif

typedef float v2f __attribute__((ext_vector_type(2)));

#if __has_builtin(__builtin_elementwise_fma)
#define FMA2(a, b, c) __builtin_elementwise_fma((a), (b), (c))
#else
static __device__ inline v2f FMA2(v2f a, v2f b, v2f c) {
    v2f r; r.x = fmaf(a.x, b.x, c.x); r.y = fmaf(a.y, b.y, c.y); return r;
}
#endif

#define LOG2E 1.44269504088896340736f
// exp(inv*dist) = exp2( CW*dot + CE*(n2+1) ), inv = -12.5, ||w||^2 == 1
#define CW (25.0f * LOG2E)
#define CE (-12.5f * LOG2E)
// feat kept at 16x reference scale -> var is 256x -> eps must be 256*1e-5
// for an EXACT match to reference BN.
#define BN_EPS_SCALED 2.56e-3f

// Barrier workspace layout (float offsets from ws base); every slot that two
// XCDs communicate through is touched ONLY by agent-scope atomics (coherence-
// point ops -> no cache maintenance ever needed):
//   [0..64)     gsum
//   [64..128)   gss
//   [128..640)  subcnt: 32 counters (q*8+j), spaced 16 floats = 1 line apart
//   [640..704)  rootcnt: 4 counters (q), spaced 16
//   [704..1216) flags: 32 copies (q*8+j), spaced 16
//   [1216..1984) wx/wy/wz tables (3 x 256)
#define WS_SUB 128
#define WS_ROOT 640
#define WS_FLAG 704
#define WS_WX 1216

// ---------------------------------------------------------------------------
// Kernel 0: zero the barrier/accumulator region (ws is poisoned 0xAA before
// every timed launch) and precompute scaled kernel directions into SoA
// (wave-uniform scalar-load path in the hot loop).
// ---------------------------------------------------------------------------
__global__ __launch_bounds__(256) void fkc_prep(
    const float* __restrict__ walpha, const float* __restrict__ wbeta,
    float* __restrict__ ws)
{
    const int t = threadIdx.x;
    for (int i = t; i < WS_WX; i += 256) ws[i] = 0.0f;
    float a = walpha[t];
    float b = wbeta[t];
    float sa = __sinf(a);
    ws[WS_WX + t]       = CW * sa * __cosf(b);
    ws[WS_WX + 256 + t] = CW * sa * __sinf(b);
    ws[WS_WX + 512 + t] = CW * __cosf(a);
}

// ---------------------------------------------------------------------------
// Fused kernel: feats -> LDS stage -> block (sum,sumsq) reduce -> atomics ->
// PER-QUARTER software barrier -> BN scale/shift -> BN+ReLU on LDS-resident
// feats -> single post-BN store. (No pre-BN out traffic, no second pass.)
//
// R3 post-mortem (fused ~100us timed / 291us profiled, VALUBusy 5.6%): the
// barrier's RELEASE fetch_add emits buffer_wbl2 (L2 tag-sweep writeback) and
// __threadfence emits buffer_inv (L1+L2 invalidate) -- 2048 of each, ~256
// serialized L2 sweeps per XCD. Plus 2048 same-line RMWs + 2048 spinners on
// ONE line at the coherence point.
// R4 barrier: ALL-RELAXED (zero cache-maintenance ops), per-k-quarter (512
// blocks; a quarter only needs its own 16 stats), 2-level counter tree
// (8 subcounters x 64 RMWs -> 8 root RMWs; max same-line RMWs 2048 -> 64),
// completion broadcast to 8 spread flag copies (<=64 spinners/line, poll
// ~0.85us apart). Ordering: __syncthreads drains vmcnt(0) so the block's
// gsum/gss coherence-point RMWs are complete before its counter RMW; flags
// are relaxed agent atomic stores (write-through); all post-barrier reads of
// gsum/gss are relaxed agent atomic loads (coherence-point reads -> can't be
// stale). Compiler memory barrier after the spin prevents hoisting; HW VMEM
// issue is in-order per wave.
//
// Geometry: 2048 blocks, 1 point/thread, 8 blocks/CU (LDS 18.75 KB x 8 =
// 150 KB; VGPR 32; 32 waves/CU). Host occupancy gate guards co-residency.
// ---------------------------------------------------------------------------
__global__ __launch_bounds__(256, 8) void fkc_fused(
    const float* __restrict__ normals,   // (B,3,N)
    const int*   __restrict__ nidx,      // (B,N,3) int32
    float* __restrict__ ws,              // barrier + tables (layout above)
    float* __restrict__ out,             // (B,K,N) final (post BN+ReLU)
    const float* __restrict__ gamma,
    const float* __restrict__ beta)
{
    __shared__ float fl[16][257];        // 16.4 KB, lives across the barrier
    __shared__ float ps[16][17], pq[16][17];
    __shared__ float scs[16], shs[16];

    const float* wx = ws + WS_WX;
    const float* wy = ws + WS_WX + 256;
    const float* wz = ws + WS_WX + 512;
    float* gsum = ws;
    float* gss  = ws + 64;

    const int tid = threadIdx.x;
    const int pg = blockIdx.x >> 2;          // point group 0..511
    const int q  = blockIdx.x & 3;           // k quarter
    const int k0 = q * 16;
    const int gid = pg * 256 + tid;
    const int b = gid >> 14;
    const int n = gid & (NN - 1);
    const float* nb = normals + b * 3 * NN;

    // Gather the 4 face points (center + 3 neighbors), all unit normals.
    float fx[4], fy[4], fz[4];
    fx[0] = nb[n];
    fy[0] = nb[NN + n];
    fz[0] = nb[2 * NN + n];
    const int ibase = (b * NN + n) * 3;
#pragma unroll
    for (int j = 0; j < 3; ++j) {
        int id = nidx[ibase + j];
        fx[j + 1] = nb[id];
        fy[j + 1] = nb[NN + id];
        fz[j + 1] = nb[2 * NN + id];
    }

    // Pack p-pairs for v_pk_fma_f32.
    v2f fx01 = {fx[0], fx[1]}, fx23 = {fx[2], fx[3]};
    v2f fy01 = {fy[0], fy[1]}, fy23 = {fy[2], fy[3]};
    v2f fz01 = {fz[0], fz[1]}, fz23 = {fz[2], fz[3]};
    v2f e01, e23;
    {
        v2f n2a = FMA2(fx01, fx01, FMA2(fy01, fy01, fz01 * fz01));
        v2f n2b = FMA2(fx23, fx23, FMA2(fy23, fy23, fz23 * fz23));
        e01 = CE * (n2a + 1.0f);
        e23 = CE * (n2b + 1.0f);
    }

#pragma unroll
    for (int kk = 0; kk < 16; ++kk) {
        v2f acc01 = {0.0f, 0.0f}, acc23 = {0.0f, 0.0f};
#pragma unroll
        for (int m = 0; m < 4; ++m) {
            const int wi = ((k0 + kk) << 2) + m;   // wave-uniform -> s_load
            float wxv = wx[wi], wyv = wy[wi], wzv = wz[wi];
            v2f wx2 = {wxv, wxv}, wy2 = {wyv, wyv}, wz2 = {wzv, wzv};
            v2f a01 = FMA2(fz01, wz2, FMA2(fy01, wy2, FMA2(fx01, wx2, e01)));
            v2f a23 = FMA2(fz23, wz2, FMA2(fy23, wy2, FMA2(fx23, wx2, e23)));
            v2f x01 = {EXP2(a01.x), EXP2(a01.y)};
            v2f x23 = {EXP2(a23.x), EXP2(a23.y)};
            acc01 += x01;
            acc23 += x23;
        }
        v2f t2 = acc01 + acc23;
        fl[kk][tid] = t2.x + t2.y;       // no pre-BN global store
    }
    __syncthreads();

    // Column-sum the stage: thread (k = tid&15, part = tid>>4) sums 16 feats.
    // Bank: (257k + 16part + r) % 32 -> 2-way aliasing only (free per m136).
    {
        const int k = tid & 15;
        const int part = tid >> 4;
        float s = 0.0f, ss = 0.0f;
#pragma unroll
        for (int r = 0; r < 16; ++r) {
            float v = fl[k][part * 16 + r];
            s += v;
            ss = fmaf(v, v, ss);
        }
        ps[k][part] = s;
        pq[k][part] = ss;
    }
    __syncthreads();

    if (tid < 16) {
        float s = 0.0f;
#pragma unroll
        for (int r = 0; r < 16; ++r) s += ps[tid][r];
        atomicAdd(&gsum[k0 + tid], s);
    } else if (tid < 32) {
        const int kk = tid - 16;
        float ss = 0.0f;
#pragma unroll
        for (int r = 0; r < 16; ++r) ss += pq[kk][r];
        atomicAdd(&gss[k0 + kk], ss);
    }

    // __syncthreads drains vmcnt(0): this block's gsum/gss RMWs have reached
    // the coherence point before tid0 touches the barrier counters.
    __syncthreads();

    // ---- per-quarter, all-relaxed, 2-level tree barrier ----
    if (tid == 0) {
        const int j = pg & 7;
        unsigned* sub  = (unsigned*)(ws + WS_SUB)  + (q * 8 + j) * 16;
        unsigned* root = (unsigned*)(ws + WS_ROOT) + q * 16;
        unsigned* flg  = (unsigned*)(ws + WS_FLAG) + (q * 8 + j) * 16;

        unsigned old = __hip_atomic_fetch_add(sub, 1u, __ATOMIC_RELAXED,
                                              __HIP_MEMORY_SCOPE_AGENT);
        if (old == 63u) {   // last of the 64 blocks in subgroup (q,j)
            unsigned r = __hip_atomic_fetch_add(root, 1u, __ATOMIC_RELAXED,
                                                __HIP_MEMORY_SCOPE_AGENT);
            if (r == 7u) {  // all 512 blocks of quarter q have arrived
#pragma unroll
                for (int jj = 0; jj < 8; ++jj) {
                    unsigned* f = (unsigned*)(ws + WS_FLAG) + (q * 8 + jj) * 16;
                    __hip_atomic_store(f, 1u, __ATOMIC_RELAXED,
                                       __HIP_MEMORY_SCOPE_AGENT);
                }
            }
        }
        // Relaxed coherence-point polls: no cache maintenance, <=64 spinners
        // per flag line, ~0.85us apart. Bounded: a violated co-residency
        // assumption shows as FAILED, never a hang.
        int polls = 0;
        while (__hip_atomic_load(flg, __ATOMIC_RELAXED,
                                 __HIP_MEMORY_SCOPE_AGENT) == 0u) {
            __builtin_amdgcn_s_sleep(32);
            if (++polls > 150000) break;
        }
        __asm__ __volatile__("" ::: "memory");  // no compiler hoisting past spin
    }
    __syncthreads();

    // BN scale/shift per k (exact: eps scaled by 256 for the 16x feat scale).
    // Relaxed agent atomic loads read the coherence point -> never stale.
    if (tid < 16) {
        const float invM = 1.0f / (float)(BB * NN);
        float s = __hip_atomic_load(&gsum[k0 + tid], __ATOMIC_RELAXED,
                                    __HIP_MEMORY_SCOPE_AGENT);
        float qq = __hip_atomic_load(&gss[k0 + tid], __ATOMIC_RELAXED,
                                     __HIP_MEMORY_SCOPE_AGENT);
        float mean = s * invM;
        float var = fmaf(-mean, mean, qq * invM);  // biased variance (x16 scale)
        float sc = gamma[k0 + tid] * rsqrtf(var + BN_EPS_SCALED);
        scs[tid] = sc;
        shs[tid] = fmaf(-mean, sc, beta[k0 + tid]);
    }
    __syncthreads();

    // Apply BN+ReLU to the LDS-resident feats; single coalesced store pass.
    float* orow = out + (b * KK + k0) * NN + n;
#pragma unroll
    for (int kk = 0; kk < 16; ++kk) {
        orow[kk * NN] = fmaxf(fmaf(fl[kk][tid], scs[kk], shs[kk]), 0.0f);
    }
}

// ---------------------------------------------------------------------------
// FALLBACK PATH (the proven 110.7 us structure): main writes pre-BN feats +
// atomics; apply does BN+ReLU in a second pass. Used only if the host-side
// occupancy check says the fused kernel cannot be fully co-resident (8/CU).
// ---------------------------------------------------------------------------
__global__ __launch_bounds__(256, 8) void fkc_main(
    const float* __restrict__ normals, const int* __restrict__ nidx,
    float* __restrict__ ws,
    float* __restrict__ out)
{
    __shared__ float fl[16][257];
    __shared__ float ps[16][17], pq[16][17];

    const float* wx = ws + WS_WX;
    const float* wy = ws + WS_WX + 256;
    const float* wz = ws + WS_WX + 512;
    float* gsum = ws;
    float* gss  = ws + 64;

    const int tid = threadIdx.x;
    const int pg = blockIdx.x >> 2;
    const int k0 = (blockIdx.x & 3) * 16;
    const int gid = pg * 256 + tid;
    const int b = gid >> 14;
    const int n = gid & (NN - 1);
    const float* nb = normals + b * 3 * NN;

    float fx[4], fy[4], fz[4];
    fx[0] = nb[n];
    fy[0] = nb[NN + n];
    fz[0] = nb[2 * NN + n];
    const int ibase = (b * NN + n) * 3;
#pragma unroll
    for (int j = 0; j < 3; ++j) {
        int id = nidx[ibase + j];
        fx[j + 1] = nb[id];
        fy[j + 1] = nb[NN + id];
        fz[j + 1] = nb[2 * NN + id];
    }

    v2f fx01 = {fx[0], fx[1]}, fx23 = {fx[2], fx[3]};
    v2f fy01 = {fy[0], fy[1]}, fy23 = {fy[2], fy[3]};
    v2f fz01 = {fz[0], fz[1]}, fz23 = {fz[2], fz[3]};
    v2f e01, e23;
    {
        v2f n2a = FMA2(fx01, fx01, FMA2(fy01, fy01, fz01 * fz01));
        v2f n2b = FMA2(fx23, fx23, FMA2(fy23, fy23, fz23 * fz23));
        e01 = CE * (n2a + 1.0f);
        e23 = CE * (n2b + 1.0f);
    }

    float* orow = out + (b * KK + k0) * NN + n;
#pragma unroll
    for (int kk = 0; kk < 16; ++kk) {
        v2f acc01 = {0.0f, 0.0f}, acc23 = {0.0f, 0.0f};
#pragma unroll
        for (int m = 0; m < 4; ++m) {
            const int wi = ((k0 + kk) << 2) + m;
            float wxv = wx[wi], wyv = wy[wi], wzv = wz[wi];
            v2f wx2 = {wxv, wxv}, wy2 = {wyv, wyv}, wz2 = {wzv, wzv};
            v2f a01 = FMA2(fz01, wz2, FMA2(fy01, wy2, FMA2(fx01, wx2, e01)));
            v2f a23 = FMA2(fz23, wz2, FMA2(fy23, wy2, FMA2(fx23, wx2, e23)));
            v2f x01 = {EXP2(a01.x), EXP2(a01.y)};
            v2f x23 = {EXP2(a23.x), EXP2(a23.y)};
            acc01 += x01;
            acc23 += x23;
        }
        v2f t2 = acc01 + acc23;
        float acc = t2.x + t2.y;
        orow[kk * NN] = acc;
        fl[kk][tid] = acc;
    }
    __syncthreads();

    {
        const int k = tid & 15;
        const int part = tid >> 4;
        float s = 0.0f, ss = 0.0f;
#pragma unroll
        for (int r = 0; r < 16; ++r) {
            float v = fl[k][part * 16 + r];
            s += v;
            ss = fmaf(v, v, ss);
        }
        ps[k][part] = s;
        pq[k][part] = ss;
    }
    __syncthreads();

    if (tid < 16) {
        float s = 0.0f;
#pragma unroll
        for (int r = 0; r < 16; ++r) s += ps[tid][r];
        atomicAdd(&gsum[k0 + tid], s);
    } else if (tid < 32) {
        const int kk = tid - 16;
        float ss = 0.0f;
#pragma unroll
        for (int r = 0; r < 16; ++r) ss += pq[kk][r];
        atomicAdd(&gss[k0 + kk], ss);
    }
}

__global__ __launch_bounds__(256) void fkc_apply(
    float4* __restrict__ out4,
    const float* __restrict__ ws,
    const float* __restrict__ gamma, const float* __restrict__ beta)
{
    const int i = blockIdx.x * 256 + threadIdx.x;
    const int k = (i >> 12) & (KK - 1);      // uniform within block

    const float invM = 1.0f / (float)(BB * NN);
    float mean = ws[k] * invM;
    float var = fmaf(-mean, mean, ws[64 + k] * invM);
    float sc = gamma[k] * rsqrtf(var + BN_EPS_SCALED);
    float sh = fmaf(-mean, sc, beta[k]);

    float4 v = out4[i];
    v.x = fmaxf(fmaf(v.x, sc, sh), 0.0f);
    v.y = fmaxf(fmaf(v.y, sc, sh), 0.0f);
    v.z = fmaxf(fmaf(v.z, sc, sh), 0.0f);
    v.w = fmaxf(fmaf(v.w, sc, sh), 0.0f);
    out4[i] = v;
}

extern "C" void kernel_launch(void* const* d_in, const int* in_sizes, int n_in,
                              void* d_out, int out_size, void* d_ws, size_t ws_size,
                              hipStream_t stream) {
    const float* normals = (const float*)d_in[0];
    const int*   nidx    = (const int*)d_in[1];
    const float* walpha  = (const float*)d_in[2];
    const float* wbeta   = (const float*)d_in[3];
    const float* gamma   = (const float*)d_in[4];
    const float* beta    = (const float*)d_in[5];
    float* out = (float*)d_out;
    float* ws = (float*)d_ws;

    // One-time host-side co-residency check (queries only — capture-safe).
    // The fused path requires all 2048 blocks resident simultaneously (8/CU).
    static int use_fused = -1;
    if (use_fused < 0) {
        int occ = 0, ncu = 0, dev = 0;
        hipError_t e1 = hipOccupancyMaxActiveBlocksPerMultiprocessor(
            &occ, fkc_fused, 256, 0);
        hipGetDevice(&dev);
        hipError_t e2 = hipDeviceGetAttribute(
            &ncu, hipDeviceAttributeMultiprocessorCount, dev);
        use_fused = (e1 == hipSuccess && e2 == hipSuccess &&
                     (long)occ * ncu >= GRID_FUSED) ? 1 : 0;
    }

    fkc_prep<<<1, 256, 0, stream>>>(walpha, wbeta, ws);
    if (use_fused) {
        fkc_fused<<<GRID_FUSED, 256, 0, stream>>>(
            normals, nidx, ws, out, gamma, beta);
    } else {
        fkc_main<<<2048, 256, 0, stream>>>(normals, nidx, ws, out);
        fkc_apply<<<8192, 256, 0, stream>>>((float4*)out, ws, gamma, beta);
    }
}